// Round 10
// baseline (269.919 us; speedup 1.0000x reference)
//
#include <hip/hip_runtime.h>
#include <stdint.h>

#define DEV __device__ __forceinline__

typedef unsigned short u16;
typedef unsigned int u32;
typedef short bh8 __attribute__((ext_vector_type(8)));
typedef float f32x4 __attribute__((ext_vector_type(4)));

// ---------- bf16 helpers (software f2bf ONLY — R4: asm cvt_pk produced NaN) ----------
DEV float bf2f(u16 v){ return __uint_as_float(((u32)v)<<16); }
DEV u16 f2bf(float f){
    u32 x = __float_as_uint(f);
    x += 0x7fffu + ((x>>16)&1u);
    return (u16)(x>>16);
}
DEV int2 pk4(float a, float b, float c, float d){
    int2 r;
    r.x = (int)((u32)f2bf(a) | ((u32)f2bf(b)<<16));
    r.y = (int)((u32)f2bf(c) | ((u32)f2bf(d)<<16));
    return r;
}
DEV bh8 ld_frag(const u16* p){
    int4 v = *(const int4*)p;
    union{ int4 i; bh8 h; } u; u.i = v; return u.h;
}
#define MFMA __builtin_amdgcn_mfma_f32_16x16x32_bf16

// Problem constants: BSZ=1, S=256, C=128, H=4, D=32, F=64. f32 I/O, bf16 internal.
//
// Session ledger:
//  R0: 4 kernels, mega 46.0, total 182.7
//  R1-R3: occupancy chase -> spills / re-fetch. NOT occupancy-limited.
//  R4: asm cvt_pk -> NaN. FAILED. Never hand-write cvt.
//  R5-R7: LN->registers fusion: allocator spills uncontrollable (WRITE 42/30/37MB).
//  R8: R0 + prep if-chain + oproj direct-store: mega 45.1, total 175.8
//  R9: ONE cooperative kernel + grid.sync: WRONG RESULTS (absmax 0.19) — coop
//      launch/grid.sync unreliable under this harness. ABANDONED.
//  R10 (this): delete ln launch WITHOUT new machinery: each mega block LNs its own
//      row via per-wave LDS scratch (LN liveness ~12 regs — no a[]/x[] co-residency,
//      unlike R5-R7), scratch aliases kfT region -> LDS unchanged 56320, 2 blocks/CU.
//      XOR swizzle ((tok&7)<<4) on BOTH scratch sides (rule #21). XCD swizzle so the
//      4 head-blocks of a row share one L2 (R5/R6: FETCH 33.6->21.5MB measured).
//      LN math instruction-identical to old ln_kernel => bit-identical output.
//      Decision metric: WRITE_SIZE must stay 16384KB (>20MB => spill => revert).

// Param block layout (elements, bf16) inside workspace:
#define P_LNW 0
#define P_LNB 128
#define P_QW  256
#define P_QB  16640
#define P_KW  16768
#define P_KB  33152
#define P_VW  33280
#define P_VB  49664
#define P_QFW 49792
#define P_QFB 50816
#define P_KFW 50848
#define P_KFB 51872
#define P_GW  51904
#define P_GB  68288
#define P_OW  68416
#define P_OB  84800
#define P_TOT 84928
#define P_CQW 84928    // [h][j][c] 4*32*128
#define P_CQB 101312   // [h][j]    4*32
#define P_CKW 101440
#define P_CKB 117824

#define NCONV 332

// ---------------- params: f32 -> bf16 block + combined q/k feature weights ----------------
__global__ void prep_params(
    const float* p0, const float* p1, const float* p2, const float* p3,
    const float* p4, const float* p5, const float* p6, const float* p7,
    const float* p8, const float* p9, const float* p10, const float* p11,
    const float* p12, const float* p13, const float* p14, const float* p15,
    u16* __restrict__ dst){
    int b = blockIdx.x, tid = threadIdx.x;
    if(b < NCONV){
        int idx = b*256 + tid;
        if(idx >= P_TOT) return;
        // if-chain (cndmask), NOT runtime-indexed local arrays (rule #20 -> scratch).
        const float* sp = p0; int base = P_LNW;
        if(idx >= P_LNB){ sp = p1;  base = P_LNB; }
        if(idx >= P_QW ){ sp = p2;  base = P_QW;  }
        if(idx >= P_QB ){ sp = p3;  base = P_QB;  }
        if(idx >= P_KW ){ sp = p4;  base = P_KW;  }
        if(idx >= P_KB ){ sp = p5;  base = P_KB;  }
        if(idx >= P_VW ){ sp = p6;  base = P_VW;  }
        if(idx >= P_VB ){ sp = p7;  base = P_VB;  }
        if(idx >= P_QFW){ sp = p8;  base = P_QFW; }
        if(idx >= P_QFB){ sp = p9;  base = P_QFB; }
        if(idx >= P_KFW){ sp = p10; base = P_KFW; }
        if(idx >= P_KFB){ sp = p11; base = P_KFB; }
        if(idx >= P_GW ){ sp = p12; base = P_GW;  }
        if(idx >= P_GB ){ sp = p13; base = P_GB;  }
        if(idx >= P_OW ){ sp = p14; base = P_OW;  }
        if(idx >= P_OB ){ sp = p15; base = P_OB;  }
        dst[idx] = f2bf(sp[idx - base]);
    } else if(b < NCONV + 128){
        // combined weights: Wc[h][j][c] = sum_d F[j][d] * W[h*32+d][c]
        int idx = (b - NCONV)*256 + tid;            // [0, 32768)
        int sel = idx >> 14;
        int rem = idx & 16383;
        int h = rem >> 12, j = (rem >> 7) & 31, c = rem & 127;
        const float* FWp = sel ? p10 : p8;
        const float* Wp  = sel ? p4  : p2;
        float s = 0.f;
        #pragma unroll
        for(int d=0; d<32; ++d)
            s += FWp[j*32+d] * Wp[(h*32+d)*128 + c];
        dst[(sel ? P_CKW : P_CQW) + h*4096 + j*128 + c] = f2bf(s);
    } else {
        // combined biases: bc[h][j] = sum_d F[j][d]*b[h*32+d] + fb[j]
        int t = tid;
        int sel = t >> 7, h = (t >> 5) & 3, j = t & 31;
        const float* FWp = sel ? p10 : p8;
        const float* FBp = sel ? p11 : p9;
        const float* Bp  = sel ? p5  : p3;
        float s = FBp[j];
        #pragma unroll
        for(int d=0; d<32; ++d)
            s += FWp[j*32+d] * Bp[h*32+d];
        dst[(sel ? P_CKB : P_CQB) + h*32 + j] = f2bf(s);
    }
}

// ---------------- mega kernel: one block per (row, head), in-block LN ----------------
// LDS (bytes), unchanged 56200 total:
//   mask_f [256 f32]      @ 0       (1024)
//   kfT    [64][264] u16  @ 1024    (33792)  kf^T [f][n], masked
//     -- prologue only: LN scratch, 4 waves x 4096B, aliases kfT[0..16384)
//   vT     [32][264] u16  @ 34816   (16896)  v^T [d][n] masked
//   qf     [256][68] u16  @ 1024    (34816)  aliases kfT(+vT head); [n][f]
//   kvT    [33][68]  u16  @ 51712   (4488)   kv^T [d][f]; row 32 = ksum
#define ST_N 264
#define ST_F 68
#define SM_KF   1024
#define SM_VT   34816
#define SM_QF   1024
#define SM_KVT  51712
#define SM_TOT  56200

__global__ __launch_bounds__(256,2)
void mega_kernel(const float* __restrict__ z, const int* __restrict__ mask,
                 const u16* __restrict__ pb, u16* __restrict__ attn){
    __shared__ __align__(16) char smem[SM_TOT];
    float* mask_f = (float*)smem;
    u16* kfT = (u16*)(smem + SM_KF);
    u16* vT  = (u16*)(smem + SM_VT);
    u16* qf  = (u16*)(smem + SM_QF);
    u16* kvT = (u16*)(smem + SM_KVT);

    int g = blockIdx.x;
    int u = (g & 7)*128 + (g >> 3);     // bijective XCD swizzle (1024 % 8 == 0)
    int row = u >> 2, h = u & 3;
    int tid = threadIdx.x, lane = tid & 63, wv = tid >> 6;
    int lm = lane & 15, quad = lane >> 4;

    mask_f[tid] = (float)mask[row*256 + tid];

    // ---- in-block LN: wave LNs its 64 tokens through 4KB wave-private scratch ----
    // Math is instruction-identical to the old ln_kernel (64-lane float2 reduce,
    // software f2bf) => bit-identical a-frags. Scratch swizzle ((tok&7)<<4) applied
    // on BOTH write and read (rule #21): kills 16-way token-stride bank conflict.
    bh8 a[4][4];
    {
        char* scr = smem + SM_KF + wv*4096;   // 16 tokens x 256B, per-wave
        int c0 = 2*lane;
        float w0 = bf2f(pb[P_LNW+c0]), w1 = bf2f(pb[P_LNW+c0+1]);
        float b0 = bf2f(pb[P_LNB+c0]), b1 = bf2f(pb[P_LNB+c0+1]);
        #pragma unroll 1
        for(int mt=0; mt<4; ++mt){
            #pragma unroll 1
            for(int i=0; i<16; ++i){
                int t = row*256 + wv*64 + mt*16 + i;
                float2 v = ((const float2*)z)[(size_t)t*64 + lane];
                float x0 = v.x, x1 = v.y;
                float s = x0 + x1, s2 = x0*x0 + x1*x1;
                #pragma unroll
                for(int o=1;o<64;o<<=1){ s += __shfl_xor(s,o,64); s2 += __shfl_xor(s2,o,64); }
                float mean = s*(1.f/128.f);
                float var  = s2*(1.f/128.f) - mean*mean;
                float rs = rsqrtf(var + 1e-5f);
                float o0 = (x0-mean)*rs*w0 + b0;
                float o1 = (x1-mean)*rs*w1 + b1;
                u32 po = (u32)f2bf(o0) | ((u32)f2bf(o1)<<16);
                *(u32*)(scr + ((i*256 + 4*lane) ^ ((i&7)<<4))) = po;
            }
            __syncthreads();   // drain scratch writes before cross-lane frag reads
            #pragma unroll
            for(int ks=0; ks<4; ++ks)
                a[mt][ks] = ld_frag((const u16*)(scr +
                                ((lm*256 + ks*64 + quad*16) ^ ((lm&7)<<4))));
            __syncthreads();   // frag reads done before scratch reuse / phase 1
        }
    }
    bh8 onesf;
    { union{int4 i; bh8 hh;} u2; u2.i.x=u2.i.y=u2.i.z=u2.i.w=0x3F803F80; onesf = u2.hh; }

    f32x4 gacc[4][2];
    // ---- phase 1 (merged): B = [ck0 ck1 | v0 v1 | g0 g1], shared A ----
    {
        f32x4 acc[4][6];
        #pragma unroll
        for(int mt=0;mt<4;++mt)
            #pragma unroll
            for(int j=0;j<6;++j) acc[mt][j] = (f32x4){0,0,0,0};
        #pragma unroll
        for(int ks=0; ks<4; ++ks){
            bh8 b[6];
            b[0] = ld_frag(pb + P_CKW + h*4096 + lm*128            + ks*32 + quad*8);
            b[1] = ld_frag(pb + P_CKW + h*4096 + (16+lm)*128       + ks*32 + quad*8);
            b[2] = ld_frag(pb + P_VW + (size_t)(h*32 + lm)*128     + ks*32 + quad*8);
            b[3] = ld_frag(pb + P_VW + (size_t)(h*32 + 16+lm)*128  + ks*32 + quad*8);
            b[4] = ld_frag(pb + P_GW + (size_t)(h*32 + lm)*128     + ks*32 + quad*8);
            b[5] = ld_frag(pb + P_GW + (size_t)(h*32 + 16+lm)*128  + ks*32 + quad*8);
            #pragma unroll
            for(int mt=0; mt<4; ++mt)
                #pragma unroll
                for(int j=0;j<6;++j)
                    acc[mt][j] = MFMA(a[mt][ks], b[j], acc[mt][j], 0,0,0);
        }
        float bk0 = bf2f(pb[P_CKB + h*32 + lm]);
        float bk1 = bf2f(pb[P_CKB + h*32 + 16 + lm]);
        float bv0 = bf2f(pb[P_VB + h*32 + lm]);
        float bv1 = bf2f(pb[P_VB + h*32 + 16 + lm]);
        float bg0 = bf2f(pb[P_GB + h*32 + lm]);
        float bg1 = bf2f(pb[P_GB + h*32 + 16 + lm]);
        #pragma unroll
        for(int mt=0; mt<4; ++mt){
            int n0 = wv*64 + mt*16 + quad*4;
            float ep0[4], em0[4], ep1[4], em1[4], v0[4], v1[4];
            #pragma unroll
            for(int r=0; r<4; ++r){
                float mk = mask_f[n0+r];
                float m0 = fminf(8.f, fmaxf(-8.f, acc[mt][0][r] + bk0));
                float m1 = fminf(8.f, fmaxf(-8.f, acc[mt][1][r] + bk1));
                ep0[r] = __expf( m0)*mk;  em0[r] = __expf(-m0)*mk;
                ep1[r] = __expf( m1)*mk;  em1[r] = __expf(-m1)*mk;
                v0[r] = (acc[mt][2][r] + bv0)*mk;
                v1[r] = (acc[mt][3][r] + bv1)*mk;
                gacc[mt][0][r] = 1.f/(1.f + __expf(-(acc[mt][4][r] + bg0)));
                gacc[mt][1][r] = 1.f/(1.f + __expf(-(acc[mt][5][r] + bg1)));
            }
            *(int2*)(kfT + (size_t)(lm   )*ST_N + n0) = pk4(ep0[0],ep0[1],ep0[2],ep0[3]);
            *(int2*)(kfT + (size_t)(lm+32)*ST_N + n0) = pk4(em0[0],em0[1],em0[2],em0[3]);
            *(int2*)(kfT + (size_t)(lm+16)*ST_N + n0) = pk4(ep1[0],ep1[1],ep1[2],ep1[3]);
            *(int2*)(kfT + (size_t)(lm+48)*ST_N + n0) = pk4(em1[0],em1[1],em1[2],em1[3]);
            *(int2*)(vT  + (size_t)(lm   )*ST_N + n0) = pk4(v0[0],v0[1],v0[2],v0[3]);
            *(int2*)(vT  + (size_t)(16+lm)*ST_N + n0) = pk4(v1[0],v1[1],v1[2],v1[3]);
        }
    }
    __syncthreads();
    // ---- phase 2: kvT[d][f] = sum_n kfT[f][n]*vT[d][n]; ksum via ones-frag ----
    {
        f32x4 acc0=(f32x4){0,0,0,0}, acc1=(f32x4){0,0,0,0}, acc2=(f32x4){0,0,0,0};
        #pragma unroll
        for(int ks=0; ks<8; ++ks){
            bh8 aa = ld_frag(kfT + (size_t)(wv*16+lm)*ST_N + ks*32 + quad*8);
            bh8 b0 = ld_frag(vT + (size_t)lm*ST_N      + ks*32 + quad*8);
            bh8 b1 = ld_frag(vT + (size_t)(16+lm)*ST_N + ks*32 + quad*8);
            acc0 = MFMA(aa, b0, acc0, 0,0,0);
            acc1 = MFMA(aa, b1, acc1, 0,0,0);
            acc2 = MFMA(aa, onesf, acc2, 0,0,0);
        }
        int f0 = wv*16 + quad*4;
        *(int2*)(kvT + (size_t)(lm   )*ST_F + f0) = pk4(acc0[0],acc0[1],acc0[2],acc0[3]);
        *(int2*)(kvT + (size_t)(16+lm)*ST_F + f0) = pk4(acc1[0],acc1[1],acc1[2],acc1[3]);
        if(lm==0)
            *(int2*)(kvT + (size_t)32*ST_F + f0) = pk4(acc2[0],acc2[1],acc2[2],acc2[3]);
    }
    __syncthreads();
    // ---- phase 3: qf[n][f] = featmap(zn·Wc_q^T + bc_q)  (aliases kfT/vT) ----
    {
        f32x4 acc[4][2];
        #pragma unroll
        for(int mt=0;mt<4;++mt){ acc[mt][0]=(f32x4){0,0,0,0}; acc[mt][1]=(f32x4){0,0,0,0}; }
        #pragma unroll
        for(int ks=0; ks<4; ++ks){
            bh8 b0 = ld_frag(pb + P_CQW + h*4096 + lm*128      + ks*32 + quad*8);
            bh8 b1 = ld_frag(pb + P_CQW + h*4096 + (16+lm)*128 + ks*32 + quad*8);
            #pragma unroll
            for(int mt=0; mt<4; ++mt){
                acc[mt][0] = MFMA(a[mt][ks], b0, acc[mt][0], 0,0,0);
                acc[mt][1] = MFMA(a[mt][ks], b1, acc[mt][1], 0,0,0);
            }
        }
        float bb0 = bf2f(pb[P_CQB + h*32 + lm]);
        float bb1 = bf2f(pb[P_CQB + h*32 + 16 + lm]);
        #pragma unroll
        for(int mt=0; mt<4; ++mt)
            #pragma unroll
            for(int r=0; r<4; ++r){
                int n = wv*64 + mt*16 + quad*4 + r;
                float m0 = fminf(8.f, fmaxf(-8.f, acc[mt][0][r] + bb0));
                float m1 = fminf(8.f, fmaxf(-8.f, acc[mt][1][r] + bb1));
                qf[n*ST_F + lm     ] = f2bf(__expf( m0));
                qf[n*ST_F + lm + 32] = f2bf(__expf(-m0));
                qf[n*ST_F + lm + 16] = f2bf(__expf( m1));
                qf[n*ST_F + lm + 48] = f2bf(__expf(-m1));
            }
    }
    __syncthreads();
    // ---- phase 4: out = (qf·kvT^T)/den * gate ----
    {
        f32x4 acc[4][3];
        #pragma unroll
        for(int mt=0;mt<4;++mt)
            #pragma unroll
            for(int nt=0;nt<3;++nt) acc[mt][nt]=(f32x4){0,0,0,0};
        #pragma unroll
        for(int ks=0; ks<2; ++ks){
            bh8 b0 = ld_frag(kvT + (size_t)lm*ST_F      + ks*32 + quad*8);
            bh8 b1 = ld_frag(kvT + (size_t)(16+lm)*ST_F + ks*32 + quad*8);
            bh8 b2 = ld_frag(kvT + (size_t)32*ST_F      + ks*32 + quad*8); // ksum, broadcast
            #pragma unroll
            for(int mt=0; mt<4; ++mt){
                bh8 aa = ld_frag(qf + (size_t)(wv*64+mt*16+lm)*ST_F + ks*32 + quad*8);
                acc[mt][0] = MFMA(aa, b0, acc[mt][0], 0,0,0);
                acc[mt][1] = MFMA(aa, b1, acc[mt][1], 0,0,0);
                acc[mt][2] = MFMA(aa, b2, acc[mt][2], 0,0,0);
            }
        }
        #pragma unroll
        for(int mt=0; mt<4; ++mt)
            #pragma unroll
            for(int r=0; r<4; ++r){
                int n = wv*64 + mt*16 + quad*4 + r;
                float rcp = 1.f / fmaxf(acc[mt][2][r], 1e-6f);
                u16* op = attn + ((size_t)row*256 + n)*128 + h*32;
                op[lm]    = f2bf(acc[mt][0][r]*rcp*gacc[mt][0][r]);
                op[16+lm] = f2bf(acc[mt][1][r]*rcp*gacc[mt][1][r]);
            }
    }
}

// ---------------- MFMA o-proj: attn(bf16) -> out(f32), x mask — direct f32 stores ----------------
__global__ __launch_bounds__(256,2)
void oproj_kernel(const u16* __restrict__ attn, const u16* __restrict__ pb,
                  const int* __restrict__ mask, float* __restrict__ out){
    int tid = threadIdx.x;
    int lane = tid&63, wv = tid>>6;
    int mhalf = (wv>>1)*64, nhalf = (wv&1)*64;
    int lm = lane&15, quad = lane>>4;
    int m0 = blockIdx.x*128;

    f32x4 acc[4][4];
    #pragma unroll
    for(int mt=0;mt<4;++mt)
        #pragma unroll
        for(int nt=0;nt<4;++nt)
            acc[mt][nt] = (f32x4){0.f,0.f,0.f,0.f};

    const u16* Abase = attn + (size_t)(m0 + mhalf + lm)*128 + quad*8;
    const u16* W = pb + P_OW;
    #pragma unroll
    for(int ks=0; ks<4; ++ks){
        bh8 a[4], b[4];
        #pragma unroll
        for(int mt=0; mt<4; ++mt)
            a[mt] = ld_frag(Abase + (size_t)mt*16*128 + ks*32);
        #pragma unroll
        for(int nt=0; nt<4; ++nt)
            b[nt] = ld_frag(W + (size_t)(nhalf + nt*16 + lm)*128 + ks*32 + quad*8);
        #pragma unroll
        for(int mt=0; mt<4; ++mt)
            #pragma unroll
            for(int nt=0; nt<4; ++nt)
                acc[mt][nt] = MFMA(a[mt], b[nt], acc[mt][nt], 0, 0, 0);
    }
    float bv[4];
    #pragma unroll
    for(int nt=0; nt<4; ++nt) bv[nt] = bf2f(pb[P_OB + nhalf + nt*16 + lm]);
    #pragma unroll
    for(int mt=0; mt<4; ++mt){
        int mrow = m0 + mhalf + mt*16 + quad*4;
        float mk[4];
        #pragma unroll
        for(int r=0;r<4;++r) mk[r] = (float)mask[mrow+r];
        #pragma unroll
        for(int r=0; r<4; ++r){
            float* orow = out + (size_t)(mrow + r)*128 + nhalf + lm;
            #pragma unroll
            for(int nt=0; nt<4; ++nt)
                orow[nt*16] = (acc[mt][nt][r] + bv[nt]) * mk[r];
        }
    }
}

// ---------------- launch: 3 kernels (ln folded into mega, zn deleted) ----------------
extern "C" void kernel_launch(void* const* d_in, const int* in_sizes, int n_in,
                              void* d_out, int out_size, void* d_ws, size_t ws_size,
                              hipStream_t stream){
    const float* z    = (const float*)d_in[0];
    const int*   mask = (const int*)d_in[1];

    char* ws = (char*)d_ws;
    const size_t MB = (size_t)1<<20;
    u16* attn = (u16*)(ws + 16*MB);     // 16 MB [t][128] bf16
    u16* pb   = (u16*)(ws + 32*MB);     // ~231 KB bf16 param block

    prep_params<<<NCONV+129,256,0,stream>>>(
        (const float*)d_in[2],  (const float*)d_in[3],  (const float*)d_in[4],  (const float*)d_in[5],
        (const float*)d_in[6],  (const float*)d_in[7],  (const float*)d_in[8],  (const float*)d_in[9],
        (const float*)d_in[10], (const float*)d_in[11], (const float*)d_in[12], (const float*)d_in[13],
        (const float*)d_in[14], (const float*)d_in[15], (const float*)d_in[16], (const float*)d_in[17],
        pb);
    mega_kernel<<<1024,256,0,stream>>>(z, mask, pb, attn);
    oproj_kernel<<<512,256,0,stream>>>(attn, pb, mask, (float*)d_out);
}

// Round 11
// 186.455 us; speedup vs baseline: 1.4476x; 1.4476x over previous
//
#include <hip/hip_runtime.h>
#include <stdint.h>

#define DEV __device__ __forceinline__

typedef unsigned short u16;
typedef unsigned int u32;
typedef short bh8 __attribute__((ext_vector_type(8)));
typedef float f32x4 __attribute__((ext_vector_type(4)));

// ---------- bf16 helpers (software f2bf ONLY — R4: asm cvt_pk produced NaN) ----------
DEV float bf2f(u16 v){ return __uint_as_float(((u32)v)<<16); }
DEV u16 f2bf(float f){
    u32 x = __float_as_uint(f);
    x += 0x7fffu + ((x>>16)&1u);
    return (u16)(x>>16);
}
DEV int2 pk4(float a, float b, float c, float d){
    int2 r;
    r.x = (int)((u32)f2bf(a) | ((u32)f2bf(b)<<16));
    r.y = (int)((u32)f2bf(c) | ((u32)f2bf(d)<<16));
    return r;
}
DEV bh8 ld_frag(const u16* p){
    int4 v = *(const int4*)p;
    union{ int4 i; bh8 h; } u; u.i = v; return u.h;
}
#define MFMA __builtin_amdgcn_mfma_f32_16x16x32_bf16

// Problem constants: BSZ=1, S=256, C=128, H=4, D=32, F=64. f32 I/O, bf16 internal.
//
// Session ledger:
//  R0: 4 kernels, mega 46.0, total 182.7
//  R1-R3: blocks/CU occupancy chase -> VGPR cliff (needs ~200 regs at 4mt/wave).
//  R4: asm cvt_pk -> NaN. FAILED.
//  R5/R6/R7/R9/R10: five LN-fusion variants ALL failed (spills or coop-launch
//      breakage). FINAL: ln stays a separate kernel. Launch overhead ~5us/launch
//      (R6/R7 evidence), not 35-45 (R5 was an outlier).
//  R8: prep if-chain + oproj direct-store: mega 45.1, total 175.8  <- baseline
//  R11 (this): mega 512-thread blocks, 8 waves x 2 mt-tiles (was 4 waves x 4).
//      Per-wave liveness halves (~95-115 regs): if allocator lands <=128 VGPR,
//      waves/CU doubles 8->16 (m69 cliff at 128). If >128: 1 block/CU x 8 waves
//      = same TLP as R8 (neutral). Gate GEMM moved to phase 3 (shares A; gacc
//      live only ph3->4). All MFMA counts identical. Decision metrics:
//      VGPR_Count <= 128 AND WRITE_SIZE == 16384.

// Param block layout (elements, bf16) inside workspace:
#define P_LNW 0
#define P_LNB 128
#define P_QW  256
#define P_QB  16640
#define P_KW  16768
#define P_KB  33152
#define P_VW  33280
#define P_VB  49664
#define P_QFW 49792
#define P_QFB 50816
#define P_KFW 50848
#define P_KFB 51872
#define P_GW  51904
#define P_GB  68288
#define P_OW  68416
#define P_OB  84800
#define P_TOT 84928
#define P_CQW 84928    // [h][j][c] 4*32*128
#define P_CQB 101312   // [h][j]    4*32
#define P_CKW 101440
#define P_CKB 117824

#define NCONV 332

// ---------------- params: f32 -> bf16 block + combined q/k feature weights ----------------
__global__ void prep_params(
    const float* p0, const float* p1, const float* p2, const float* p3,
    const float* p4, const float* p5, const float* p6, const float* p7,
    const float* p8, const float* p9, const float* p10, const float* p11,
    const float* p12, const float* p13, const float* p14, const float* p15,
    u16* __restrict__ dst){
    int b = blockIdx.x, tid = threadIdx.x;
    if(b < NCONV){
        int idx = b*256 + tid;
        if(idx >= P_TOT) return;
        // if-chain (cndmask), NOT runtime-indexed local arrays (rule #20 -> scratch).
        const float* sp = p0; int base = P_LNW;
        if(idx >= P_LNB){ sp = p1;  base = P_LNB; }
        if(idx >= P_QW ){ sp = p2;  base = P_QW;  }
        if(idx >= P_QB ){ sp = p3;  base = P_QB;  }
        if(idx >= P_KW ){ sp = p4;  base = P_KW;  }
        if(idx >= P_KB ){ sp = p5;  base = P_KB;  }
        if(idx >= P_VW ){ sp = p6;  base = P_VW;  }
        if(idx >= P_VB ){ sp = p7;  base = P_VB;  }
        if(idx >= P_QFW){ sp = p8;  base = P_QFW; }
        if(idx >= P_QFB){ sp = p9;  base = P_QFB; }
        if(idx >= P_KFW){ sp = p10; base = P_KFW; }
        if(idx >= P_KFB){ sp = p11; base = P_KFB; }
        if(idx >= P_GW ){ sp = p12; base = P_GW;  }
        if(idx >= P_GB ){ sp = p13; base = P_GB;  }
        if(idx >= P_OW ){ sp = p14; base = P_OW;  }
        if(idx >= P_OB ){ sp = p15; base = P_OB;  }
        dst[idx] = f2bf(sp[idx - base]);
    } else if(b < NCONV + 128){
        // combined weights: Wc[h][j][c] = sum_d F[j][d] * W[h*32+d][c]
        int idx = (b - NCONV)*256 + tid;            // [0, 32768)
        int sel = idx >> 14;
        int rem = idx & 16383;
        int h = rem >> 12, j = (rem >> 7) & 31, c = rem & 127;
        const float* FWp = sel ? p10 : p8;
        const float* Wp  = sel ? p4  : p2;
        float s = 0.f;
        #pragma unroll
        for(int d=0; d<32; ++d)
            s += FWp[j*32+d] * Wp[(h*32+d)*128 + c];
        dst[(sel ? P_CKW : P_CQW) + h*4096 + j*128 + c] = f2bf(s);
    } else {
        // combined biases: bc[h][j] = sum_d F[j][d]*b[h*32+d] + fb[j]
        int t = tid;
        int sel = t >> 7, h = (t >> 5) & 3, j = t & 31;
        const float* FWp = sel ? p10 : p8;
        const float* FBp = sel ? p11 : p9;
        const float* Bp  = sel ? p5  : p3;
        float s = FBp[j];
        #pragma unroll
        for(int d=0; d<32; ++d)
            s += FWp[j*32+d] * Bp[h*32+d];
        dst[(sel ? P_CKB : P_CQB) + h*32 + j] = f2bf(s);
    }
}

// ---------------- LayerNorm: one wave per token (f32 in, bf16 out) ----------------
__global__ void ln_kernel(const float* __restrict__ zv, const u16* __restrict__ pb,
                          u16* __restrict__ zn){
    int t = blockIdx.x*4 + (threadIdx.x>>6);
    int lane = threadIdx.x & 63;
    float2 v = ((const float2*)zv)[(size_t)t*64 + lane];
    float x0 = v.x, x1 = v.y;
    float s = x0 + x1, s2 = x0*x0 + x1*x1;
    #pragma unroll
    for(int o=1;o<64;o<<=1){ s += __shfl_xor(s,o,64); s2 += __shfl_xor(s2,o,64); }
    float mean = s*(1.f/128.f);
    float var  = s2*(1.f/128.f) - mean*mean;
    float rs = rsqrtf(var + 1e-5f);
    int c0 = 2*lane;
    float w0 = bf2f(pb[P_LNW+c0]), w1 = bf2f(pb[P_LNW+c0+1]);
    float b0 = bf2f(pb[P_LNB+c0]), b1 = bf2f(pb[P_LNB+c0+1]);
    float o0 = (x0-mean)*rs*w0 + b0;
    float o1 = (x1-mean)*rs*w1 + b1;
    u32 po = (u32)f2bf(o0) | ((u32)f2bf(o1)<<16);
    *(u32*)(zn + (size_t)t*128 + c0) = po;
}

// ---------------- mega kernel: one block per (row, head), 512 threads / 8 waves ----------------
// LDS (bytes) — identical layout to R8:
//   mask_f [256 f32]      @ 0       (1024)
//   kfT    [64][264] u16  @ 1024    (33792)  kf^T [f][n], masked
//   vT     [32][264] u16  @ 34816   (16896)  v^T [d][n] masked
//   qf     [256][68] u16  @ 1024    (34816)  aliases kfT(+vT head); [n][f]
//   kvT    [33][68]  u16  @ 51712   (4488)   kv^T [d][f]; row 32 = ksum
// Wave split: wave wv in [0,8) owns n-range [wv*32, wv*32+32) = 2 mt-tiles of 16.
// Phase 2: wave = (f-group wv>>1)*16 rows x (d-half wv&1)*16 cols.
#define ST_N 264
#define ST_F 68
#define SM_KF   1024
#define SM_VT   34816
#define SM_QF   1024
#define SM_KVT  51712
#define SM_TOT  56200

__global__ __launch_bounds__(512,2)
void mega_kernel(const u16* __restrict__ zn, const int* __restrict__ mask,
                 const u16* __restrict__ pb, u16* __restrict__ attn){
    __shared__ __align__(16) char smem[SM_TOT];
    float* mask_f = (float*)smem;
    u16* kfT = (u16*)(smem + SM_KF);
    u16* vT  = (u16*)(smem + SM_VT);
    u16* qf  = (u16*)(smem + SM_QF);
    u16* kvT = (u16*)(smem + SM_KVT);

    int g = blockIdx.x, row = g>>2, h = g&3;
    int tid = threadIdx.x, lane = tid & 63, wv = tid >> 6;   // wv in [0,8)
    int lm = lane & 15, quad = lane >> 4;

    if(tid < 256) mask_f[tid] = (float)mask[row*256 + tid];

    // zn A-frags: 2 mt-tiles per wave, reused by phases 1 and 3
    bh8 a[2][4];
    {
        const u16* Ab = zn + ((size_t)row*256 + wv*32 + lm)*128 + quad*8;
        #pragma unroll
        for(int mt=0; mt<2; ++mt)
            #pragma unroll
            for(int ks=0; ks<4; ++ks)
                a[mt][ks] = ld_frag(Ab + (size_t)mt*16*128 + ks*32);
    }
    bh8 onesf;
    { union{int4 i; bh8 h;} u; u.i.x=u.i.y=u.i.z=u.i.w=0x3F803F80; onesf = u.h; }

    __syncthreads();

    // ---- phase 1: B = [ck0 ck1 | v0 v1] (gate moved to phase 3) ----
    {
        f32x4 acc[2][4];
        #pragma unroll
        for(int mt=0;mt<2;++mt)
            #pragma unroll
            for(int j=0;j<4;++j) acc[mt][j] = (f32x4){0,0,0,0};
        #pragma unroll
        for(int ks=0; ks<4; ++ks){
            bh8 b[4];
            b[0] = ld_frag(pb + P_CKW + h*4096 + lm*128            + ks*32 + quad*8);
            b[1] = ld_frag(pb + P_CKW + h*4096 + (16+lm)*128       + ks*32 + quad*8);
            b[2] = ld_frag(pb + P_VW + (size_t)(h*32 + lm)*128     + ks*32 + quad*8);
            b[3] = ld_frag(pb + P_VW + (size_t)(h*32 + 16+lm)*128  + ks*32 + quad*8);
            #pragma unroll
            for(int mt=0; mt<2; ++mt)
                #pragma unroll
                for(int j=0;j<4;++j)
                    acc[mt][j] = MFMA(a[mt][ks], b[j], acc[mt][j], 0,0,0);
        }
        float bk0 = bf2f(pb[P_CKB + h*32 + lm]);
        float bk1 = bf2f(pb[P_CKB + h*32 + 16 + lm]);
        float bv0 = bf2f(pb[P_VB + h*32 + lm]);
        float bv1 = bf2f(pb[P_VB + h*32 + 16 + lm]);
        #pragma unroll
        for(int mt=0; mt<2; ++mt){
            int n0 = wv*32 + mt*16 + quad*4;
            float ep0[4], em0[4], ep1[4], em1[4], v0[4], v1[4];
            #pragma unroll
            for(int r=0; r<4; ++r){
                float mk = mask_f[n0+r];
                float m0 = fminf(8.f, fmaxf(-8.f, acc[mt][0][r] + bk0));
                float m1 = fminf(8.f, fmaxf(-8.f, acc[mt][1][r] + bk1));
                ep0[r] = __expf( m0)*mk;  em0[r] = __expf(-m0)*mk;
                ep1[r] = __expf( m1)*mk;  em1[r] = __expf(-m1)*mk;
                v0[r] = (acc[mt][2][r] + bv0)*mk;
                v1[r] = (acc[mt][3][r] + bv1)*mk;
            }
            *(int2*)(kfT + (size_t)(lm   )*ST_N + n0) = pk4(ep0[0],ep0[1],ep0[2],ep0[3]);
            *(int2*)(kfT + (size_t)(lm+32)*ST_N + n0) = pk4(em0[0],em0[1],em0[2],em0[3]);
            *(int2*)(kfT + (size_t)(lm+16)*ST_N + n0) = pk4(ep1[0],ep1[1],ep1[2],ep1[3]);
            *(int2*)(kfT + (size_t)(lm+48)*ST_N + n0) = pk4(em1[0],em1[1],em1[2],em1[3]);
            *(int2*)(vT  + (size_t)(lm   )*ST_N + n0) = pk4(v0[0],v0[1],v0[2],v0[3]);
            *(int2*)(vT  + (size_t)(16+lm)*ST_N + n0) = pk4(v1[0],v1[1],v1[2],v1[3]);
        }
    }
    __syncthreads();
    // ---- phase 2: kvT[d][f] = sum_n kfT[f][n]*vT[d][n]; 8 waves = 4 f-grp x 2 d-half ----
    {
        int fw = wv >> 1, dw = wv & 1;
        f32x4 acc0=(f32x4){0,0,0,0}, acc2=(f32x4){0,0,0,0};
        #pragma unroll
        for(int ks=0; ks<8; ++ks){
            bh8 aa = ld_frag(kfT + (size_t)(fw*16+lm)*ST_N + ks*32 + quad*8);
            bh8 b0 = ld_frag(vT + (size_t)(dw*16+lm)*ST_N + ks*32 + quad*8);
            acc0 = MFMA(aa, b0, acc0, 0,0,0);
            if(dw == 0)   // wave-uniform branch
                acc2 = MFMA(aa, onesf, acc2, 0,0,0);
        }
        int f0 = fw*16 + quad*4;
        *(int2*)(kvT + (size_t)(dw*16+lm)*ST_F + f0) = pk4(acc0[0],acc0[1],acc0[2],acc0[3]);
        if(dw==0 && lm==0)
            *(int2*)(kvT + (size_t)32*ST_F + f0) = pk4(acc2[0],acc2[1],acc2[2],acc2[3]);
    }
    __syncthreads();
    // ---- phase 3: qf[n][f] = featmap(zn·Wc_q^T + bc_q); gate GEMM here (shares A) ----
    f32x4 gacc[2][2];
    {
        f32x4 acc[2][4];
        #pragma unroll
        for(int mt=0;mt<2;++mt)
            #pragma unroll
            for(int j=0;j<4;++j) acc[mt][j] = (f32x4){0,0,0,0};
        #pragma unroll
        for(int ks=0; ks<4; ++ks){
            bh8 b[4];
            b[0] = ld_frag(pb + P_CQW + h*4096 + lm*128            + ks*32 + quad*8);
            b[1] = ld_frag(pb + P_CQW + h*4096 + (16+lm)*128       + ks*32 + quad*8);
            b[2] = ld_frag(pb + P_GW + (size_t)(h*32 + lm)*128     + ks*32 + quad*8);
            b[3] = ld_frag(pb + P_GW + (size_t)(h*32 + 16+lm)*128  + ks*32 + quad*8);
            #pragma unroll
            for(int mt=0; mt<2; ++mt)
                #pragma unroll
                for(int j=0;j<4;++j)
                    acc[mt][j] = MFMA(a[mt][ks], b[j], acc[mt][j], 0,0,0);
        }
        float bb0 = bf2f(pb[P_CQB + h*32 + lm]);
        float bb1 = bf2f(pb[P_CQB + h*32 + 16 + lm]);
        float bg0 = bf2f(pb[P_GB + h*32 + lm]);
        float bg1 = bf2f(pb[P_GB + h*32 + 16 + lm]);
        #pragma unroll
        for(int mt=0; mt<2; ++mt)
            #pragma unroll
            for(int r=0; r<4; ++r){
                int n = wv*32 + mt*16 + quad*4 + r;
                float m0 = fminf(8.f, fmaxf(-8.f, acc[mt][0][r] + bb0));
                float m1 = fminf(8.f, fmaxf(-8.f, acc[mt][1][r] + bb1));
                qf[n*ST_F + lm     ] = f2bf(__expf( m0));
                qf[n*ST_F + lm + 32] = f2bf(__expf(-m0));
                qf[n*ST_F + lm + 16] = f2bf(__expf( m1));
                qf[n*ST_F + lm + 48] = f2bf(__expf(-m1));
                gacc[mt][0][r] = 1.f/(1.f + __expf(-(acc[mt][2][r] + bg0)));
                gacc[mt][1][r] = 1.f/(1.f + __expf(-(acc[mt][3][r] + bg1)));
            }
    }
    __syncthreads();
    // ---- phase 4: out = (qf·kvT^T)/den * gate ----
    {
        f32x4 acc[2][3];
        #pragma unroll
        for(int mt=0;mt<2;++mt)
            #pragma unroll
            for(int nt=0;nt<3;++nt) acc[mt][nt]=(f32x4){0,0,0,0};
        #pragma unroll
        for(int ks=0; ks<2; ++ks){
            bh8 b0 = ld_frag(kvT + (size_t)lm*ST_F      + ks*32 + quad*8);
            bh8 b1 = ld_frag(kvT + (size_t)(16+lm)*ST_F + ks*32 + quad*8);
            bh8 b2 = ld_frag(kvT + (size_t)32*ST_F      + ks*32 + quad*8); // ksum, broadcast
            #pragma unroll
            for(int mt=0; mt<2; ++mt){
                bh8 aa = ld_frag(qf + (size_t)(wv*32+mt*16+lm)*ST_F + ks*32 + quad*8);
                acc[mt][0] = MFMA(aa, b0, acc[mt][0], 0,0,0);
                acc[mt][1] = MFMA(aa, b1, acc[mt][1], 0,0,0);
                acc[mt][2] = MFMA(aa, b2, acc[mt][2], 0,0,0);
            }
        }
        #pragma unroll
        for(int mt=0; mt<2; ++mt)
            #pragma unroll
            for(int r=0; r<4; ++r){
                int n = wv*32 + mt*16 + quad*4 + r;
                float rcp = 1.f / fmaxf(acc[mt][2][r], 1e-6f);
                u16* op = attn + ((size_t)row*256 + n)*128 + h*32;
                op[lm]    = f2bf(acc[mt][0][r]*rcp*gacc[mt][0][r]);
                op[16+lm] = f2bf(acc[mt][1][r]*rcp*gacc[mt][1][r]);
            }
    }
}

// ---------------- MFMA o-proj: attn(bf16) -> out(f32), x mask — direct f32 stores ----------------
__global__ __launch_bounds__(256,2)
void oproj_kernel(const u16* __restrict__ attn, const u16* __restrict__ pb,
                  const int* __restrict__ mask, float* __restrict__ out){
    int tid = threadIdx.x;
    int lane = tid&63, wv = tid>>6;
    int mhalf = (wv>>1)*64, nhalf = (wv&1)*64;
    int lm = lane&15, quad = lane>>4;
    int m0 = blockIdx.x*128;

    f32x4 acc[4][4];
    #pragma unroll
    for(int mt=0;mt<4;++mt)
        #pragma unroll
        for(int nt=0;nt<4;++nt)
            acc[mt][nt] = (f32x4){0.f,0.f,0.f,0.f};

    const u16* Abase = attn + (size_t)(m0 + mhalf + lm)*128 + quad*8;
    const u16* W = pb + P_OW;
    #pragma unroll
    for(int ks=0; ks<4; ++ks){
        bh8 a[4], b[4];
        #pragma unroll
        for(int mt=0; mt<4; ++mt)
            a[mt] = ld_frag(Abase + (size_t)mt*16*128 + ks*32);
        #pragma unroll
        for(int nt=0; nt<4; ++nt)
            b[nt] = ld_frag(W + (size_t)(nhalf + nt*16 + lm)*128 + ks*32 + quad*8);
        #pragma unroll
        for(int mt=0; mt<4; ++mt)
            #pragma unroll
            for(int nt=0; nt<4; ++nt)
                acc[mt][nt] = MFMA(a[mt], b[nt], acc[mt][nt], 0, 0, 0);
    }
    float bv[4];
    #pragma unroll
    for(int nt=0; nt<4; ++nt) bv[nt] = bf2f(pb[P_OB + nhalf + nt*16 + lm]);
    #pragma unroll
    for(int mt=0; mt<4; ++mt){
        int mrow = m0 + mhalf + mt*16 + quad*4;
        float mk[4];
        #pragma unroll
        for(int r=0;r<4;++r) mk[r] = (float)mask[mrow+r];
        #pragma unroll
        for(int r=0; r<4; ++r){
            float* orow = out + (size_t)(mrow + r)*128 + nhalf + lm;
            #pragma unroll
            for(int nt=0; nt<4; ++nt)
                orow[nt*16] = (acc[mt][nt][r] + bv[nt]) * mk[r];
        }
    }
}

// ---------------- launch: 4 kernels (R8 structure; mega now 512-thread) ----------------
extern "C" void kernel_launch(void* const* d_in, const int* in_sizes, int n_in,
                              void* d_out, int out_size, void* d_ws, size_t ws_size,
                              hipStream_t stream){
    const float* z    = (const float*)d_in[0];
    const int*   mask = (const int*)d_in[1];

    char* ws = (char*)d_ws;
    const size_t MB = (size_t)1<<20;
    u16* zn   = (u16*)(ws + 0*MB);      // 16 MB [t][128] bf16
    u16* attn = (u16*)(ws + 16*MB);     // 16 MB [t][128] bf16
    u16* pb   = (u16*)(ws + 32*MB);     // ~231 KB bf16 param block

    prep_params<<<NCONV+129,256,0,stream>>>(
        (const float*)d_in[2],  (const float*)d_in[3],  (const float*)d_in[4],  (const float*)d_in[5],
        (const float*)d_in[6],  (const float*)d_in[7],  (const float*)d_in[8],  (const float*)d_in[9],
        (const float*)d_in[10], (const float*)d_in[11], (const float*)d_in[12], (const float*)d_in[13],
        (const float*)d_in[14], (const float*)d_in[15], (const float*)d_in[16], (const float*)d_in[17],
        pb);
    ln_kernel<<<16384,256,0,stream>>>(z, pb, zn);
    mega_kernel<<<1024,512,0,stream>>>(zn, mask, pb, attn);
    oproj_kernel<<<512,256,0,stream>>>(attn, pb, mask, (float*)d_out);
}

// Round 12
// 174.403 us; speedup vs baseline: 1.5477x; 1.0691x over previous
//
#include <hip/hip_runtime.h>
#include <stdint.h>

#define DEV __device__ __forceinline__

typedef unsigned short u16;
typedef unsigned int u32;
typedef short bh8 __attribute__((ext_vector_type(8)));
typedef float f32x4 __attribute__((ext_vector_type(4)));

// ---------- bf16 helpers (software f2bf ONLY — R4: asm cvt_pk produced NaN) ----------
DEV float bf2f(u16 v){ return __uint_as_float(((u32)v)<<16); }
DEV u16 f2bf(float f){
    u32 x = __float_as_uint(f);
    x += 0x7fffu + ((x>>16)&1u);
    return (u16)(x>>16);
}
DEV int2 pk4(float a, float b, float c, float d){
    int2 r;
    r.x = (int)((u32)f2bf(a) | ((u32)f2bf(b)<<16));
    r.y = (int)((u32)f2bf(c) | ((u32)f2bf(d)<<16));
    return r;
}
DEV bh8 ld_frag(const u16* p){
    int4 v = *(const int4*)p;
    union{ int4 i; bh8 h; } u; u.i = v; return u.h;
}
#define MFMA __builtin_amdgcn_mfma_f32_16x16x32_bf16

// Problem constants: BSZ=1, S=256, C=128, H=4, D=32, F=64. f32 I/O, bf16 internal.
//
// Session ledger:
//  R0: 4 kernels, mega 46.0, total 182.7
//  R1-R3: blocks/CU occupancy chase -> VGPR cliff / re-fetch. Not occupancy-bound.
//  R4: asm cvt_pk -> NaN. FAILED.
//  R5/R6/R7/R9/R10: five LN-fusion-into-mega variants ALL failed. ln stays separate.
//  R8: prep if-chain + oproj direct-store: mega 45.1, total 175.8  <- baseline
//  R11: 512-thread mega: occ 40.5%, VGPR 56, no spills — and SLOWER (63us).
//      FINAL: mega is barrier/serial-chain-bound; R8's 4-wave body is the optimum.
//  R12 (this): mega = exact R8. prep+ln MERGED into one kernel (independent once
//      ln reads f32 ln_w/ln_b directly; test ln_w=1,ln_b=0 -> bit-identical zn).
//      ln grid-strided: 16384 tiny blocks -> 2048 blocks x 32 tokens (G11).
//      4 launches -> 3. Decision: total <172 = launch/grid overhead confirmed;
//      >=172 = fixed harness overhead, declare plateau.

// Param block layout (elements, bf16) inside workspace:
#define P_LNW 0
#define P_LNB 128
#define P_QW  256
#define P_QB  16640
#define P_KW  16768
#define P_KB  33152
#define P_VW  33280
#define P_VB  49664
#define P_QFW 49792
#define P_QFB 50816
#define P_KFW 50848
#define P_KFB 51872
#define P_GW  51904
#define P_GB  68288
#define P_OW  68416
#define P_OB  84800
#define P_TOT 84928
#define P_CQW 84928    // [h][j][c] 4*32*128
#define P_CQB 101312   // [h][j]    4*32
#define P_CKW 101440
#define P_CKB 117824

#define NCONV 332
#define LN_BLOCKS 2048     // 2048 blocks x 32 tokens = 65536 tokens

// ---------------- prep + LN merged (independent work, one launch) ----------------
__global__ void prep_ln_kernel(
    const float* p0, const float* p1, const float* p2, const float* p3,
    const float* p4, const float* p5, const float* p6, const float* p7,
    const float* p8, const float* p9, const float* p10, const float* p11,
    const float* p12, const float* p13, const float* p14, const float* p15,
    u16* __restrict__ dst,
    const float* __restrict__ z, u16* __restrict__ zn){
    int b = blockIdx.x, tid = threadIdx.x;
    if(b < NCONV){
        int idx = b*256 + tid;
        if(idx >= P_TOT) return;
        // if-chain (cndmask), NOT runtime-indexed local arrays (rule #20 -> scratch).
        const float* sp = p0; int base = P_LNW;
        if(idx >= P_LNB){ sp = p1;  base = P_LNB; }
        if(idx >= P_QW ){ sp = p2;  base = P_QW;  }
        if(idx >= P_QB ){ sp = p3;  base = P_QB;  }
        if(idx >= P_KW ){ sp = p4;  base = P_KW;  }
        if(idx >= P_KB ){ sp = p5;  base = P_KB;  }
        if(idx >= P_VW ){ sp = p6;  base = P_VW;  }
        if(idx >= P_VB ){ sp = p7;  base = P_VB;  }
        if(idx >= P_QFW){ sp = p8;  base = P_QFW; }
        if(idx >= P_QFB){ sp = p9;  base = P_QFB; }
        if(idx >= P_KFW){ sp = p10; base = P_KFW; }
        if(idx >= P_KFB){ sp = p11; base = P_KFB; }
        if(idx >= P_GW ){ sp = p12; base = P_GW;  }
        if(idx >= P_GB ){ sp = p13; base = P_GB;  }
        if(idx >= P_OW ){ sp = p14; base = P_OW;  }
        if(idx >= P_OB ){ sp = p15; base = P_OB;  }
        dst[idx] = f2bf(sp[idx - base]);
    } else if(b < NCONV + 128){
        // combined weights: Wc[h][j][c] = sum_d F[j][d] * W[h*32+d][c]
        int idx = (b - NCONV)*256 + tid;            // [0, 32768)
        int sel = idx >> 14;
        int rem = idx & 16383;
        int h = rem >> 12, j = (rem >> 7) & 31, c = rem & 127;
        const float* FWp = sel ? p10 : p8;
        const float* Wp  = sel ? p4  : p2;
        float s = 0.f;
        #pragma unroll
        for(int d=0; d<32; ++d)
            s += FWp[j*32+d] * Wp[(h*32+d)*128 + c];
        dst[(sel ? P_CKW : P_CQW) + h*4096 + j*128 + c] = f2bf(s);
    } else if(b == NCONV + 128){
        // combined biases: bc[h][j] = sum_d F[j][d]*b[h*32+d] + fb[j]
        int t = tid;
        int sel = t >> 7, h = (t >> 5) & 3, j = t & 31;
        const float* FWp = sel ? p10 : p8;
        const float* FBp = sel ? p11 : p9;
        const float* Bp  = sel ? p5  : p3;
        float s = FBp[j];
        #pragma unroll
        for(int d=0; d<32; ++d)
            s += FWp[j*32+d] * Bp[h*32+d];
        dst[(sel ? P_CKB : P_CQB) + h*32 + j] = f2bf(s);
    } else {
        // ---- LayerNorm, grid-strided: 32 tokens/block, 8 per wave ----
        // Reads ln_w/ln_b from the f32 inputs directly (independent of prep part).
        // Test data: ln_w=1, ln_b=0 -> f2bf exact -> zn bit-identical to R8's ln.
        int lb = b - (NCONV + 129);                 // [0, LN_BLOCKS)
        int lane = tid & 63, wv = tid >> 6;
        int c0 = 2*lane;
        float w0 = p0[c0], w1 = p0[c0+1];
        float b0 = p1[c0], b1 = p1[c0+1];
        #pragma unroll 1
        for(int it=0; it<8; ++it){
            int t = lb*32 + it*4 + wv;
            float2 v = ((const float2*)z)[(size_t)t*64 + lane];
            float x0 = v.x, x1 = v.y;
            float s = x0 + x1, s2 = x0*x0 + x1*x1;
            #pragma unroll
            for(int o=1;o<64;o<<=1){ s += __shfl_xor(s,o,64); s2 += __shfl_xor(s2,o,64); }
            float mean = s*(1.f/128.f);
            float var  = s2*(1.f/128.f) - mean*mean;
            float rs = rsqrtf(var + 1e-5f);
            float o0 = (x0-mean)*rs*w0 + b0;
            float o1 = (x1-mean)*rs*w1 + b1;
            u32 po = (u32)f2bf(o0) | ((u32)f2bf(o1)<<16);
            *(u32*)(zn + (size_t)t*128 + c0) = po;
        }
    }
}

// ---------------- mega kernel: one block per (row, head) [exact R8 body, 45.1us] ----------------
// LDS (bytes):
//   mask_f [256 f32]      @ 0       (1024)
//   kfT    [64][264] u16  @ 1024    (33792)  kf^T [f][n], masked
//   vT     [32][264] u16  @ 34816   (16896)  v^T [d][n] masked
//   qf     [256][68] u16  @ 1024    (34816)  aliases kfT(+vT head); [n][f]
//   kvT    [33][68]  u16  @ 51712   (4488)   kv^T [d][f]; row 32 = ksum
#define ST_N 264
#define ST_F 68
#define SM_KF   1024
#define SM_VT   34816
#define SM_QF   1024
#define SM_KVT  51712
#define SM_TOT  56200

__global__ __launch_bounds__(256,2)
void mega_kernel(const u16* __restrict__ zn, const int* __restrict__ mask,
                 const u16* __restrict__ pb, u16* __restrict__ attn){
    __shared__ __align__(16) char smem[SM_TOT];
    float* mask_f = (float*)smem;
    u16* kfT = (u16*)(smem + SM_KF);
    u16* vT  = (u16*)(smem + SM_VT);
    u16* qf  = (u16*)(smem + SM_QF);
    u16* kvT = (u16*)(smem + SM_KVT);

    int g = blockIdx.x, row = g>>2, h = g&3;
    int tid = threadIdx.x, lane = tid & 63, wv = tid >> 6;
    int lm = lane & 15, quad = lane >> 4;

    mask_f[tid] = (float)mask[row*256 + tid];

    // zn A-frags: loaded once, reused by all GEMM phases
    bh8 a[4][4];
    {
        const u16* Ab = zn + ((size_t)row*256 + wv*64 + lm)*128 + quad*8;
        #pragma unroll
        for(int mt=0; mt<4; ++mt)
            #pragma unroll
            for(int ks=0; ks<4; ++ks)
                a[mt][ks] = ld_frag(Ab + (size_t)mt*16*128 + ks*32);
    }
    bh8 onesf;
    { union{int4 i; bh8 h;} u; u.i.x=u.i.y=u.i.z=u.i.w=0x3F803F80; onesf = u.h; }

    __syncthreads();

    f32x4 gacc[4][2];
    // ---- phase 1 (merged): B = [ck0 ck1 | v0 v1 | g0 g1], shared A ----
    {
        f32x4 acc[4][6];
        #pragma unroll
        for(int mt=0;mt<4;++mt)
            #pragma unroll
            for(int j=0;j<6;++j) acc[mt][j] = (f32x4){0,0,0,0};
        #pragma unroll
        for(int ks=0; ks<4; ++ks){
            bh8 b[6];
            b[0] = ld_frag(pb + P_CKW + h*4096 + lm*128            + ks*32 + quad*8);
            b[1] = ld_frag(pb + P_CKW + h*4096 + (16+lm)*128       + ks*32 + quad*8);
            b[2] = ld_frag(pb + P_VW + (size_t)(h*32 + lm)*128     + ks*32 + quad*8);
            b[3] = ld_frag(pb + P_VW + (size_t)(h*32 + 16+lm)*128  + ks*32 + quad*8);
            b[4] = ld_frag(pb + P_GW + (size_t)(h*32 + lm)*128     + ks*32 + quad*8);
            b[5] = ld_frag(pb + P_GW + (size_t)(h*32 + 16+lm)*128  + ks*32 + quad*8);
            #pragma unroll
            for(int mt=0; mt<4; ++mt)
                #pragma unroll
                for(int j=0;j<6;++j)
                    acc[mt][j] = MFMA(a[mt][ks], b[j], acc[mt][j], 0,0,0);
        }
        float bk0 = bf2f(pb[P_CKB + h*32 + lm]);
        float bk1 = bf2f(pb[P_CKB + h*32 + 16 + lm]);
        float bv0 = bf2f(pb[P_VB + h*32 + lm]);
        float bv1 = bf2f(pb[P_VB + h*32 + 16 + lm]);
        float bg0 = bf2f(pb[P_GB + h*32 + lm]);
        float bg1 = bf2f(pb[P_GB + h*32 + 16 + lm]);
        #pragma unroll
        for(int mt=0; mt<4; ++mt){
            int n0 = wv*64 + mt*16 + quad*4;
            float ep0[4], em0[4], ep1[4], em1[4], v0[4], v1[4];
            #pragma unroll
            for(int r=0; r<4; ++r){
                float mk = mask_f[n0+r];
                float m0 = fminf(8.f, fmaxf(-8.f, acc[mt][0][r] + bk0));
                float m1 = fminf(8.f, fmaxf(-8.f, acc[mt][1][r] + bk1));
                ep0[r] = __expf( m0)*mk;  em0[r] = __expf(-m0)*mk;
                ep1[r] = __expf( m1)*mk;  em1[r] = __expf(-m1)*mk;
                v0[r] = (acc[mt][2][r] + bv0)*mk;
                v1[r] = (acc[mt][3][r] + bv1)*mk;
                gacc[mt][0][r] = 1.f/(1.f + __expf(-(acc[mt][4][r] + bg0)));
                gacc[mt][1][r] = 1.f/(1.f + __expf(-(acc[mt][5][r] + bg1)));
            }
            *(int2*)(kfT + (size_t)(lm   )*ST_N + n0) = pk4(ep0[0],ep0[1],ep0[2],ep0[3]);
            *(int2*)(kfT + (size_t)(lm+32)*ST_N + n0) = pk4(em0[0],em0[1],em0[2],em0[3]);
            *(int2*)(kfT + (size_t)(lm+16)*ST_N + n0) = pk4(ep1[0],ep1[1],ep1[2],ep1[3]);
            *(int2*)(kfT + (size_t)(lm+48)*ST_N + n0) = pk4(em1[0],em1[1],em1[2],em1[3]);
            *(int2*)(vT  + (size_t)(lm   )*ST_N + n0) = pk4(v0[0],v0[1],v0[2],v0[3]);
            *(int2*)(vT  + (size_t)(16+lm)*ST_N + n0) = pk4(v1[0],v1[1],v1[2],v1[3]);
        }
    }
    __syncthreads();
    // ---- phase 2: kvT[d][f] = sum_n kfT[f][n]*vT[d][n]; ksum via ones-frag ----
    {
        f32x4 acc0=(f32x4){0,0,0,0}, acc1=(f32x4){0,0,0,0}, acc2=(f32x4){0,0,0,0};
        #pragma unroll
        for(int ks=0; ks<8; ++ks){
            bh8 aa = ld_frag(kfT + (size_t)(wv*16+lm)*ST_N + ks*32 + quad*8);
            bh8 b0 = ld_frag(vT + (size_t)lm*ST_N      + ks*32 + quad*8);
            bh8 b1 = ld_frag(vT + (size_t)(16+lm)*ST_N + ks*32 + quad*8);
            acc0 = MFMA(aa, b0, acc0, 0,0,0);
            acc1 = MFMA(aa, b1, acc1, 0,0,0);
            acc2 = MFMA(aa, onesf, acc2, 0,0,0);
        }
        int f0 = wv*16 + quad*4;
        *(int2*)(kvT + (size_t)(lm   )*ST_F + f0) = pk4(acc0[0],acc0[1],acc0[2],acc0[3]);
        *(int2*)(kvT + (size_t)(16+lm)*ST_F + f0) = pk4(acc1[0],acc1[1],acc1[2],acc1[3]);
        if(lm==0)
            *(int2*)(kvT + (size_t)32*ST_F + f0) = pk4(acc2[0],acc2[1],acc2[2],acc2[3]);
    }
    __syncthreads();
    // ---- phase 3: qf[n][f] = featmap(zn·Wc_q^T + bc_q)  (aliases kfT/vT) ----
    {
        f32x4 acc[4][2];
        #pragma unroll
        for(int mt=0;mt<4;++mt){ acc[mt][0]=(f32x4){0,0,0,0}; acc[mt][1]=(f32x4){0,0,0,0}; }
        #pragma unroll
        for(int ks=0; ks<4; ++ks){
            bh8 b0 = ld_frag(pb + P_CQW + h*4096 + lm*128      + ks*32 + quad*8);
            bh8 b1 = ld_frag(pb + P_CQW + h*4096 + (16+lm)*128 + ks*32 + quad*8);
            #pragma unroll
            for(int mt=0; mt<4; ++mt){
                acc[mt][0] = MFMA(a[mt][ks], b0, acc[mt][0], 0,0,0);
                acc[mt][1] = MFMA(a[mt][ks], b1, acc[mt][1], 0,0,0);
            }
        }
        float bb0 = bf2f(pb[P_CQB + h*32 + lm]);
        float bb1 = bf2f(pb[P_CQB + h*32 + 16 + lm]);
        #pragma unroll
        for(int mt=0; mt<4; ++mt)
            #pragma unroll
            for(int r=0; r<4; ++r){
                int n = wv*64 + mt*16 + quad*4 + r;
                float m0 = fminf(8.f, fmaxf(-8.f, acc[mt][0][r] + bb0));
                float m1 = fminf(8.f, fmaxf(-8.f, acc[mt][1][r] + bb1));
                qf[n*ST_F + lm     ] = f2bf(__expf( m0));
                qf[n*ST_F + lm + 32] = f2bf(__expf(-m0));
                qf[n*ST_F + lm + 16] = f2bf(__expf( m1));
                qf[n*ST_F + lm + 48] = f2bf(__expf(-m1));
            }
    }
    __syncthreads();
    // ---- phase 4: out = (qf·kvT^T)/den * gate ----
    {
        f32x4 acc[4][3];
        #pragma unroll
        for(int mt=0;mt<4;++mt)
            #pragma unroll
            for(int nt=0;nt<3;++nt) acc[mt][nt]=(f32x4){0,0,0,0};
        #pragma unroll
        for(int ks=0; ks<2; ++ks){
            bh8 b0 = ld_frag(kvT + (size_t)lm*ST_F      + ks*32 + quad*8);
            bh8 b1 = ld_frag(kvT + (size_t)(16+lm)*ST_F + ks*32 + quad*8);
            bh8 b2 = ld_frag(kvT + (size_t)32*ST_F      + ks*32 + quad*8); // ksum, broadcast
            #pragma unroll
            for(int mt=0; mt<4; ++mt){
                bh8 aa = ld_frag(qf + (size_t)(wv*64+mt*16+lm)*ST_F + ks*32 + quad*8);
                acc[mt][0] = MFMA(aa, b0, acc[mt][0], 0,0,0);
                acc[mt][1] = MFMA(aa, b1, acc[mt][1], 0,0,0);
                acc[mt][2] = MFMA(aa, b2, acc[mt][2], 0,0,0);
            }
        }
        #pragma unroll
        for(int mt=0; mt<4; ++mt)
            #pragma unroll
            for(int r=0; r<4; ++r){
                int n = wv*64 + mt*16 + quad*4 + r;
                float rcp = 1.f / fmaxf(acc[mt][2][r], 1e-6f);
                u16* op = attn + ((size_t)row*256 + n)*128 + h*32;
                op[lm]    = f2bf(acc[mt][0][r]*rcp*gacc[mt][0][r]);
                op[16+lm] = f2bf(acc[mt][1][r]*rcp*gacc[mt][1][r]);
            }
    }
}

// ---------------- MFMA o-proj: attn(bf16) -> out(f32), x mask — direct f32 stores ----------------
__global__ __launch_bounds__(256,2)
void oproj_kernel(const u16* __restrict__ attn, const u16* __restrict__ pb,
                  const int* __restrict__ mask, float* __restrict__ out){
    int tid = threadIdx.x;
    int lane = tid&63, wv = tid>>6;
    int mhalf = (wv>>1)*64, nhalf = (wv&1)*64;
    int lm = lane&15, quad = lane>>4;
    int m0 = blockIdx.x*128;

    f32x4 acc[4][4];
    #pragma unroll
    for(int mt=0;mt<4;++mt)
        #pragma unroll
        for(int nt=0;nt<4;++nt)
            acc[mt][nt] = (f32x4){0.f,0.f,0.f,0.f};

    const u16* Abase = attn + (size_t)(m0 + mhalf + lm)*128 + quad*8;
    const u16* W = pb + P_OW;
    #pragma unroll
    for(int ks=0; ks<4; ++ks){
        bh8 a[4], b[4];
        #pragma unroll
        for(int mt=0; mt<4; ++mt)
            a[mt] = ld_frag(Abase + (size_t)mt*16*128 + ks*32);
        #pragma unroll
        for(int nt=0; nt<4; ++nt)
            b[nt] = ld_frag(W + (size_t)(nhalf + nt*16 + lm)*128 + ks*32 + quad*8);
        #pragma unroll
        for(int mt=0; mt<4; ++mt)
            #pragma unroll
            for(int nt=0; nt<4; ++nt)
                acc[mt][nt] = MFMA(a[mt], b[nt], acc[mt][nt], 0, 0, 0);
    }
    float bv[4];
    #pragma unroll
    for(int nt=0; nt<4; ++nt) bv[nt] = bf2f(pb[P_OB + nhalf + nt*16 + lm]);
    #pragma unroll
    for(int mt=0; mt<4; ++mt){
        int mrow = m0 + mhalf + mt*16 + quad*4;
        float mk[4];
        #pragma unroll
        for(int r=0;r<4;++r) mk[r] = (float)mask[mrow+r];
        #pragma unroll
        for(int r=0; r<4; ++r){
            float* orow = out + (size_t)(mrow + r)*128 + nhalf + lm;
            #pragma unroll
            for(int nt=0; nt<4; ++nt)
                orow[nt*16] = (acc[mt][nt][r] + bv[nt]) * mk[r];
        }
    }
}

// ---------------- launch: 3 kernels (prep+ln merged; mega/oproj = R8) ----------------
extern "C" void kernel_launch(void* const* d_in, const int* in_sizes, int n_in,
                              void* d_out, int out_size, void* d_ws, size_t ws_size,
                              hipStream_t stream){
    const float* z    = (const float*)d_in[0];
    const int*   mask = (const int*)d_in[1];

    char* ws = (char*)d_ws;
    const size_t MB = (size_t)1<<20;
    u16* zn   = (u16*)(ws + 0*MB);      // 16 MB [t][128] bf16
    u16* attn = (u16*)(ws + 16*MB);     // 16 MB [t][128] bf16
    u16* pb   = (u16*)(ws + 32*MB);     // ~231 KB bf16 param block

    prep_ln_kernel<<<NCONV+129+LN_BLOCKS,256,0,stream>>>(
        (const float*)d_in[2],  (const float*)d_in[3],  (const float*)d_in[4],  (const float*)d_in[5],
        (const float*)d_in[6],  (const float*)d_in[7],  (const float*)d_in[8],  (const float*)d_in[9],
        (const float*)d_in[10], (const float*)d_in[11], (const float*)d_in[12], (const float*)d_in[13],
        (const float*)d_in[14], (const float*)d_in[15], (const float*)d_in[16], (const float*)d_in[17],
        pb, z, zn);
    mega_kernel<<<1024,256,0,stream>>>(zn, mask, pb, attn);
    oproj_kernel<<<512,256,0,stream>>>(attn, pb, mask, (float*)d_out);
}